// Round 11
// baseline (854.598 us; speedup 1.0000x reference)
//
#include <hip/hip_runtime.h>
#include <hip/hip_bf16.h>

// RCNN: bidirectional simple-RNN + conv1x1 + global max pool + dense sigmoid
// B=256 T=512 V=50000 E=128 H=256 C=128
//
// Round-11: EW vocab table + gather-seeded R4 recurrence + pipelined convpool.
//  - EW[V][640] bf16 = [Wf^T e + bf | Wb^T e + bb | Wc_mid^T e] per VOCAB row
//    (50k rows, not 131k tokens). rnn gathers its xw C-seed from EW[idx];
//    convpool gathers the e_cur conv partial from cols [512,640).
//  - rnn: R4 config (32 blocks, 8 waves x 32 cols, 2 waves/SIMD, C-seeded
//    MFMA, T-unroll x2, LDS-only barrier) = measured-375us body; h stored
//    linearly to hstore (posted writes). Gathers proven free in R9.
//  - convpool: R10's MFMA pool + software-pipelined idx/ec gathers (R10
//    loaded them unpipelined inside the barriered t-loop -> exposed latency).
//  - ws needs 199 MB for this path; if ws_size is smaller, fall back to the
//    R10 structure (embxw + in-place rnn + ECmid), which needs 148 MB.

#define B_ 256
#define T_ 512
#define E_ 128
#define H_ 256
#define C_ 128
#define V_ 50000

typedef __attribute__((ext_vector_type(8))) short short8;
typedef __attribute__((ext_vector_type(4))) float float4v;
typedef __attribute__((ext_vector_type(2))) unsigned int uint2v;
typedef __attribute__((ext_vector_type(4))) int int4v;

__device__ inline unsigned short f2bf(float f) {
  unsigned u = __float_as_uint(f);
  u += 0x7fffu + ((u >> 16) & 1u);  // RNE
  return (unsigned short)(u >> 16);
}
__device__ inline unsigned pkbf(float a, float b) {
  __hip_bfloat162 h2 = __float22bfloat162_rn(float2{a, b});
  union { __hip_bfloat162 h; unsigned u; } cv;
  cv.h = h2;
  return cv.u;
}
__device__ inline float lo16f(unsigned u) { return __uint_as_float(u << 16); }
__device__ inline float hi16f(unsigned u) { return __uint_as_float(u & 0xffff0000u); }
__device__ inline float fast_tanh(float x) {
  float e = __expf(2.f * x);                 // inf ok -> 1
  float r = __builtin_amdgcn_rcpf(e + 1.f);
  return __builtin_fmaf(-2.f, r, 1.f);
}
__device__ inline unsigned enc_f(float f) {
  unsigned u = __float_as_uint(f);
  return (u & 0x80000000u) ? ~u : (u | 0x80000000u);
}
__device__ inline float dec_f(unsigned key) {
  unsigned bits = (key & 0x80000000u) ? (key ^ 0x80000000u) : ~key;
  return __uint_as_float(bits);
}
__device__ inline void sync_lds() {
  asm volatile("s_waitcnt lgkmcnt(0)\n\ts_barrier" ::: "memory");
}
__device__ inline int clampt(int t) { return t < 0 ? 0 : (t > 511 ? 511 : t); }

// ---------------------------------------------------------------------------
// prep: all weight transposes (both paths). WfT/WbT:[256][128] WcT:[128][640]
// UfT/UbT:[256][256], WT_all[640][128]=[Wf^T;Wb^T;Wc_mid^T], biasEW[640].
// ---------------------------------------------------------------------------
__global__ __launch_bounds__(256) void prep_kernel(
    const float* __restrict__ Wf, const float* __restrict__ Wb,
    const float* __restrict__ Wc, const float* __restrict__ Uf,
    const float* __restrict__ Ub, const float* __restrict__ bf_,
    const float* __restrict__ bb_,
    unsigned short* __restrict__ WfT, unsigned short* __restrict__ WbT,
    unsigned short* __restrict__ WcT, unsigned short* __restrict__ UfT,
    unsigned short* __restrict__ UbT, unsigned short* __restrict__ WT_all,
    float* __restrict__ biasEW) {
  int gid = blockIdx.x * 256 + threadIdx.x;
  int stride = gridDim.x * 256;
  for (int i = gid; i < 128 * 256; i += stride) {  // Wf/Wb [128][256]
    int k = i >> 8, n = i & 255;
    unsigned short vf = f2bf(Wf[i]), vb = f2bf(Wb[i]);
    WfT[n * 128 + k] = vf;
    WbT[n * 128 + k] = vb;
    WT_all[n * 128 + k] = vf;
    WT_all[(256 + n) * 128 + k] = vb;
  }
  for (int i = gid; i < 640 * 128; i += stride) {  // Wc [640][128]
    int k = i >> 7, n = i & 127;
    unsigned short v = f2bf(Wc[i]);
    WcT[n * 640 + k] = v;
    if (k >= 256 && k < 384) WT_all[(512 + n) * 128 + (k - 256)] = v;
  }
  for (int i = gid; i < 256 * 256; i += stride) {  // Uf/Ub [256][256]
    int k = i >> 8, n = i & 255;
    UfT[n * 256 + k] = f2bf(Uf[i]);
    UbT[n * 256 + k] = f2bf(Ub[i]);
  }
  for (int i = gid; i < 640; i += stride)
    biasEW[i] = i < 256 ? bf_[i] : (i < 512 ? bb_[i - 256] : 0.f);
}

// ---------------------------------------------------------------------------
// ew: EW[V][640] = emb @ [Wf|Wb|Wc_mid] + biasEW, bf16. grid 3125 x 256 thr.
// ---------------------------------------------------------------------------
__global__ __launch_bounds__(256) void ew_kernel(
    const float* __restrict__ emb, const unsigned short* __restrict__ WT_all,
    const float* __restrict__ biasEW, unsigned short* __restrict__ EW) {
  const int r0 = blockIdx.x * 16;
  const int tid = threadIdx.x;
  const int w = tid >> 6, lane = tid & 63, q = lane >> 4, l15 = lane & 15;

  short8 wfr[10][4];
#pragma unroll
  for (int mt = 0; mt < 10; ++mt)
#pragma unroll
    for (int kt = 0; kt < 4; ++kt)
      wfr[mt][kt] = *(const short8*)(WT_all + (160 * w + 16 * mt + l15) * 128 +
                                     kt * 32 + q * 8);
  short8 efr[4];
#pragma unroll
  for (int kt = 0; kt < 4; ++kt) {
    const float* p8 = emb + (size_t)(r0 + l15) * E_ + kt * 32 + q * 8;
    float4v a0 = *(const float4v*)p8;
    float4v a1 = *(const float4v*)(p8 + 4);
    union { unsigned u[4]; short8 s; } cv;
    cv.u[0] = pkbf(a0[0], a0[1]);
    cv.u[1] = pkbf(a0[2], a0[3]);
    cv.u[2] = pkbf(a1[0], a1[1]);
    cv.u[3] = pkbf(a1[2], a1[3]);
    efr[kt] = cv.s;
  }
  float4v acc[10];
#pragma unroll
  for (int mt = 0; mt < 10; ++mt) acc[mt] = (float4v){0.f, 0.f, 0.f, 0.f};
#pragma unroll
  for (int kt = 0; kt < 4; ++kt)
#pragma unroll
    for (int mt = 0; mt < 10; ++mt)
      acc[mt] = __builtin_amdgcn_mfma_f32_16x16x32_bf16(wfr[mt][kt], efr[kt],
                                                        acc[mt], 0, 0, 0);
#pragma unroll
  for (int mt = 0; mt < 10; ++mt) {
    const int col = 160 * w + 16 * mt + 4 * q;
    float4v bv = *(const float4v*)(biasEW + col);
    float4v v = acc[mt] + bv;
    uint2v pk = {pkbf(v[0], v[1]), pkbf(v[2], v[3])};
    *(uint2v*)(EW + (size_t)(r0 + l15) * 640 + col) = pk;
  }
}

// ---------------------------------------------------------------------------
// embxw (FALLBACK): xw^T = W^T e^T + b into xwh. grid (128,16,2), 256 thr.
// ---------------------------------------------------------------------------
__global__ __launch_bounds__(256) void embxw_kernel(
    const int* __restrict__ idxL, const int* __restrict__ idxR,
    const float* __restrict__ emb,
    const unsigned short* __restrict__ WfT, const unsigned short* __restrict__ WbT,
    const float* __restrict__ bfv, const float* __restrict__ bbv,
    unsigned short* __restrict__ xwh) {
  const int dir = blockIdx.z;
  const int t0 = blockIdx.x * 4;
  const int b0 = blockIdx.y * 16;
  const int tid = threadIdx.x;
  const int w = tid >> 6, lane = tid & 63, q = lane >> 4, l15 = lane & 15;

  const int* __restrict__ idx = dir ? idxR : idxL;
  const unsigned short* __restrict__ WT = dir ? WbT : WfT;
  const float* __restrict__ bias = dir ? bbv : bfv;

  short8 wfr[4][4];
#pragma unroll
  for (int mt = 0; mt < 4; ++mt)
#pragma unroll
    for (int kt = 0; kt < 4; ++kt)
      wfr[mt][kt] = *(const short8*)(WT + (64 * w + 16 * mt + l15) * 128 +
                                     kt * 32 + q * 8);
  float4v bv[4];
#pragma unroll
  for (int mt = 0; mt < 4; ++mt)
    bv[mt] = *(const float4v*)(bias + 64 * w + 16 * mt + 4 * q);

#pragma unroll 1
  for (int j = 0; j < 4; ++j) {
    const int t = t0 + j;
    const int er = idx[(b0 + l15) * T_ + t];
    const float* ep = emb + (size_t)er * E_;
    short8 efr[4];
#pragma unroll
    for (int kt = 0; kt < 4; ++kt) {
      const float* p8 = ep + kt * 32 + q * 8;
      float4v a0 = *(const float4v*)p8;
      float4v a1 = *(const float4v*)(p8 + 4);
      union { unsigned u[4]; short8 s; } cv;
      cv.u[0] = pkbf(a0[0], a0[1]);
      cv.u[1] = pkbf(a0[2], a0[3]);
      cv.u[2] = pkbf(a1[0], a1[1]);
      cv.u[3] = pkbf(a1[2], a1[3]);
      efr[kt] = cv.s;
    }
    float4v acc[4];
#pragma unroll
    for (int mt = 0; mt < 4; ++mt) acc[mt] = (float4v){0.f, 0.f, 0.f, 0.f};
#pragma unroll
    for (int kt = 0; kt < 4; ++kt)
#pragma unroll
      for (int mt = 0; mt < 4; ++mt)
        acc[mt] = __builtin_amdgcn_mfma_f32_16x16x32_bf16(wfr[mt][kt], efr[kt],
                                                          acc[mt], 0, 0, 0);
#pragma unroll
    for (int mt = 0; mt < 4; ++mt) {
      float4v v = acc[mt] + bv[mt];
      uint2v pk = {pkbf(v[0], v[1]), pkbf(v[2], v[3])};
      *(uint2v*)(xwh +
                 ((size_t)(dir * 256 + b0 + 4 * w + mt) * T_ + t) * 256 +
                 lane * 4) = pk;
    }
  }
}

// ---------------------------------------------------------------------------
// ewmid (FALLBACK): ECmid[V][128] = Wc_mid^T emb^T. grid 3125 x 256 thr.
// ---------------------------------------------------------------------------
__global__ __launch_bounds__(256) void ewmid_kernel(
    const float* __restrict__ emb, const unsigned short* __restrict__ WcT,
    unsigned short* __restrict__ ECmid) {
  const int r0 = blockIdx.x * 16;
  const int tid = threadIdx.x;
  const int w = tid >> 6, lane = tid & 63, q = lane >> 4, l15 = lane & 15;

  short8 wfr[2][4];
#pragma unroll
  for (int mt = 0; mt < 2; ++mt)
#pragma unroll
    for (int kt = 0; kt < 4; ++kt)
      wfr[mt][kt] = *(const short8*)(WcT +
                                     (size_t)(32 * w + 16 * mt + l15) * 640 +
                                     256 + kt * 32 + q * 8);
  short8 efr[4];
#pragma unroll
  for (int kt = 0; kt < 4; ++kt) {
    const float* p8 = emb + (size_t)(r0 + l15) * E_ + kt * 32 + q * 8;
    float4v a0 = *(const float4v*)p8;
    float4v a1 = *(const float4v*)(p8 + 4);
    union { unsigned u[4]; short8 s; } cv;
    cv.u[0] = pkbf(a0[0], a0[1]);
    cv.u[1] = pkbf(a0[2], a0[3]);
    cv.u[2] = pkbf(a1[0], a1[1]);
    cv.u[3] = pkbf(a1[2], a1[3]);
    efr[kt] = cv.s;
  }
  float4v acc[2];
  acc[0] = (float4v){0.f, 0.f, 0.f, 0.f};
  acc[1] = (float4v){0.f, 0.f, 0.f, 0.f};
#pragma unroll
  for (int kt = 0; kt < 4; ++kt)
#pragma unroll
    for (int mt = 0; mt < 2; ++mt)
      acc[mt] = __builtin_amdgcn_mfma_f32_16x16x32_bf16(wfr[mt][kt], efr[kt],
                                                        acc[mt], 0, 0, 0);
#pragma unroll
  for (int mt = 0; mt < 2; ++mt) {
    uint2v pk = {pkbf(acc[mt][0], acc[mt][1]), pkbf(acc[mt][2], acc[mt][3])};
    *(uint2v*)(ECmid + (size_t)(r0 + l15) * 128 + 32 * w + 16 * mt + 4 * q) =
        pk;
  }
}

// ---------------------------------------------------------------------------
// rnn_gather: R4 body, C-seed gathered from EW, h stored to hstore.
// 32 blocks x 512 thr (8 waves x 32 cols). Unroll x2, 1-pair gather pipeline.
// ---------------------------------------------------------------------------
__global__ __launch_bounds__(512, 2) void rnn_gather_kernel(
    const int* __restrict__ idxL, const int* __restrict__ idxR,
    const unsigned short* __restrict__ EW,
    const unsigned short* __restrict__ UfT,
    const unsigned short* __restrict__ UbT,
    unsigned short* __restrict__ hstore) {
  const int dir = blockIdx.x & 1;
  const int b0 = (blockIdx.x >> 1) * 16;
  const int* __restrict__ idx = dir ? idxR : idxL;
  const unsigned short* __restrict__ UT = dir ? UbT : UfT;
  const int ewoff = dir ? 256 : 0;
  const int tstep = dir ? -1 : 1;
  const int t0 = dir ? (T_ - 1) : 0;
  const ptrdiff_t dstep = (ptrdiff_t)tstep * 256;

  const int tid = threadIdx.x;
  const int wv = tid >> 6, lane = tid & 63, q = lane >> 4, l15 = lane & 15;

  __shared__ __attribute__((aligned(16))) unsigned short hbuf[2][16][280];
  unsigned short* hb0 = &hbuf[0][0][0];
  unsigned short* hb1 = &hbuf[1][0][0];
  for (int i = tid; i < 16 * 280; i += 512) hb0[i] = 0;

  short8 ufr[2][8];
#pragma unroll
  for (int mt = 0; mt < 2; ++mt)
#pragma unroll
    for (int kt = 0; kt < 8; ++kt)
      ufr[mt][kt] = *(const short8*)(UT + (32 * wv + 16 * mt + l15) * H_ +
                                     kt * 32 + q * 8);

  const int idxbase = (b0 + l15) * T_;
  const int eofs = ewoff + 32 * wv + 4 * q;

  int i0A = idx[idxbase + t0];
  int i0B = idx[idxbase + t0 + tstep];
  int ihA = idx[idxbase + t0 + 2 * tstep];
  int ihB = idx[idxbase + t0 + 3 * tstep];
  uint2v curA[2], curB[2];
#pragma unroll
  for (int mt = 0; mt < 2; ++mt) {
    curA[mt] = *(const uint2v*)(EW + (size_t)i0A * 640 + eofs + 16 * mt);
    curB[mt] = *(const uint2v*)(EW + (size_t)i0B * 640 + eofs + 16 * mt);
  }

  unsigned short* ptrS[2];
#pragma unroll
  for (int mt = 0; mt < 2; ++mt)
    ptrS[mt] = hstore + (size_t)(dir * 256 + b0 + 2 * wv + mt) * T_ * 256 +
               lane * 4 + (ptrdiff_t)t0 * 256;

  const unsigned lrd = l15 * 280;
  const unsigned lwr = l15 * 280 + 32 * wv;

  __syncthreads();

  int tA = t0;
#pragma unroll 1
  for (int p = 0; p < 256; ++p) {
    int ilA = idx[idxbase + clampt(tA + 4 * tstep)];
    int ilB = idx[idxbase + clampt(tA + 5 * tstep)];
    uint2v nxtA[2], nxtB[2];
#pragma unroll
    for (int mt = 0; mt < 2; ++mt) {
      nxtA[mt] = *(const uint2v*)(EW + (size_t)ihA * 640 + eofs + 16 * mt);
      nxtB[mt] = *(const uint2v*)(EW + (size_t)ihB * 640 + eofs + 16 * mt);
    }

    // ---- STEP A: read hb0, write hb1 ----
    {
      short8 afr[8];
#pragma unroll
      for (int kt = 0; kt < 8; ++kt)
        afr[kt] = *(const short8*)(hb0 + lrd + kt * 32 + q * 8);
      float4v acc[2];
#pragma unroll
      for (int mt = 0; mt < 2; ++mt)
        acc[mt] = (float4v){lo16f(curA[mt].x), hi16f(curA[mt].x),
                            lo16f(curA[mt].y), hi16f(curA[mt].y)};
#pragma unroll
      for (int kt = 0; kt < 8; ++kt)
#pragma unroll
        for (int mt = 0; mt < 2; ++mt)
          acc[mt] = __builtin_amdgcn_mfma_f32_16x16x32_bf16(
              ufr[mt][kt], afr[kt], acc[mt], 0, 0, 0);
#pragma unroll
      for (int mt = 0; mt < 2; ++mt) {
        uint2v hv = {pkbf(fast_tanh(acc[mt][0]), fast_tanh(acc[mt][1])),
                     pkbf(fast_tanh(acc[mt][2]), fast_tanh(acc[mt][3]))};
        *(uint2v*)(hb1 + lwr + 16 * mt + 4 * q) = hv;
        *(uint2v*)ptrS[mt] = hv;
      }
    }
    sync_lds();

    // ---- STEP B: read hb1, write hb0 ----
    {
      short8 afr[8];
#pragma unroll
      for (int kt = 0; kt < 8; ++kt)
        afr[kt] = *(const short8*)(hb1 + lrd + kt * 32 + q * 8);
      float4v acc[2];
#pragma unroll
      for (int mt = 0; mt < 2; ++mt)
        acc[mt] = (float4v){lo16f(curB[mt].x), hi16f(curB[mt].x),
                            lo16f(curB[mt].y), hi16f(curB[mt].y)};
#pragma unroll
      for (int kt = 0; kt < 8; ++kt)
#pragma unroll
        for (int mt = 0; mt < 2; ++mt)
          acc[mt] = __builtin_amdgcn_mfma_f32_16x16x32_bf16(
              ufr[mt][kt], afr[kt], acc[mt], 0, 0, 0);
#pragma unroll
      for (int mt = 0; mt < 2; ++mt) {
        uint2v hv = {pkbf(fast_tanh(acc[mt][0]), fast_tanh(acc[mt][1])),
                     pkbf(fast_tanh(acc[mt][2]), fast_tanh(acc[mt][3]))};
        *(uint2v*)(hb0 + lwr + 16 * mt + 4 * q) = hv;
        *(uint2v*)(ptrS[mt] + dstep) = hv;
      }
    }
#pragma unroll
    for (int mt = 0; mt < 2; ++mt) {
      ptrS[mt] += 2 * dstep;
      curA[mt] = nxtA[mt];
      curB[mt] = nxtB[mt];
    }
    ihA = ilA;
    ihB = ilB;
    tA += 2 * tstep;
    sync_lds();
  }
}

// ---------------------------------------------------------------------------
// rnn_inplace (FALLBACK): exact R4/R10 — C-seed from xwh, h in place.
// ---------------------------------------------------------------------------
__global__ __launch_bounds__(512, 2) void rnn_inplace_kernel(
    unsigned short* xwh, const unsigned short* __restrict__ UfT,
    const unsigned short* __restrict__ UbT) {
  const int dir = blockIdx.x & 1;
  const int b0 = (blockIdx.x >> 1) * 16;
  const unsigned short* __restrict__ UT = dir ? UbT : UfT;
  const int tstep = dir ? -1 : 1;
  const int t0 = dir ? (T_ - 1) : 0;
  const ptrdiff_t dstep = (ptrdiff_t)tstep * 256;

  const int tid = threadIdx.x;
  const int wv = tid >> 6, lane = tid & 63, q = lane >> 4, l15 = lane & 15;

  __shared__ __attribute__((aligned(16))) unsigned short hbuf[2][16][280];
  unsigned short* hb0 = &hbuf[0][0][0];
  unsigned short* hb1 = &hbuf[1][0][0];
  for (int i = tid; i < 16 * 280; i += 512) hb0[i] = 0;

  short8 ufr[2][8];
#pragma unroll
  for (int mt = 0; mt < 2; ++mt)
#pragma unroll
    for (int kt = 0; kt < 8; ++kt)
      ufr[mt][kt] = *(const short8*)(UT + (32 * wv + 16 * mt + l15) * H_ +
                                     kt * 32 + q * 8);

  unsigned short* ptrS[2];
  const unsigned short* ptrL[2];
  uint2v curA[2], curB[2], infA[2], infB[2];
#pragma unroll
  for (int mt = 0; mt < 2; ++mt) {
    unsigned short* base =
        xwh + (size_t)(dir * 256 + b0 + 2 * wv + mt) * T_ * 256 + lane * 4;
    unsigned short* bt = base + (ptrdiff_t)t0 * 256;
    curA[mt] = *(const uint2v*)(bt);
    curB[mt] = *(const uint2v*)(bt + dstep);
    infA[mt] = *(const uint2v*)(bt + 2 * dstep);
    infB[mt] = *(const uint2v*)(bt + 3 * dstep);
    ptrS[mt] = bt;
    ptrL[mt] = bt + 4 * dstep;
  }

  const unsigned lrd = l15 * 280;
  const unsigned lwr = l15 * 280 + 32 * wv;

  __syncthreads();

#pragma unroll 1
  for (int p = 0; p < 256; ++p) {
    uint2v ldA[2], ldB[2];
    if (p < 254) {
#pragma unroll
      for (int mt = 0; mt < 2; ++mt) {
        ldA[mt] = *(const uint2v*)(ptrL[mt]);
        ldB[mt] = *(const uint2v*)(ptrL[mt] + dstep);
      }
    } else {
#pragma unroll
      for (int mt = 0; mt < 2; ++mt) { ldA[mt] = infA[mt]; ldB[mt] = infB[mt]; }
    }
#pragma unroll
    for (int mt = 0; mt < 2; ++mt) ptrL[mt] += 2 * dstep;

    {
      short8 afr[8];
#pragma unroll
      for (int kt = 0; kt < 8; ++kt)
        afr[kt] = *(const short8*)(hb0 + lrd + kt * 32 + q * 8);
      float4v acc[2];
#pragma unroll
      for (int mt = 0; mt < 2; ++mt)
        acc[mt] = (float4v){lo16f(curA[mt].x), hi16f(curA[mt].x),
                            lo16f(curA[mt].y), hi16f(curA[mt].y)};
#pragma unroll
      for (int kt = 0; kt < 8; ++kt)
#pragma unroll
        for (int mt = 0; mt < 2; ++mt)
          acc[mt] = __builtin_amdgcn_mfma_f32_16x16x32_bf16(
              ufr[mt][kt], afr[kt], acc[mt], 0, 0, 0);
#pragma unroll
      for (int mt = 0; mt < 2; ++mt) {
        uint2v hv = {pkbf(fast_tanh(acc[mt][0]), fast_tanh(acc[mt][1])),
                     pkbf(fast_tanh(acc[mt][2]), fast_tanh(acc[mt][3]))};
        *(uint2v*)(hb1 + lwr + 16 * mt + 4 * q) = hv;
        *(uint2v*)ptrS[mt] = hv;
      }
    }
    sync_lds();

    {
      short8 afr[8];
#pragma unroll
      for (int kt = 0; kt < 8; ++kt)
        afr[kt] = *(const short8*)(hb1 + lrd + kt * 32 + q * 8);
      float4v acc[2];
#pragma unroll
      for (int mt = 0; mt < 2; ++mt)
        acc[mt] = (float4v){lo16f(curB[mt].x), hi16f(curB[mt].x),
                            lo16f(curB[mt].y), hi16f(curB[mt].y)};
#pragma unroll
      for (int kt = 0; kt < 8; ++kt)
#pragma unroll
        for (int mt = 0; mt < 2; ++mt)
          acc[mt] = __builtin_amdgcn_mfma_f32_16x16x32_bf16(
              ufr[mt][kt], afr[kt], acc[mt], 0, 0, 0);
#pragma unroll
      for (int mt = 0; mt < 2; ++mt) {
        uint2v hv = {pkbf(fast_tanh(acc[mt][0]), fast_tanh(acc[mt][1])),
                     pkbf(fast_tanh(acc[mt][2]), fast_tanh(acc[mt][3]))};
        *(uint2v*)(hb0 + lwr + 16 * mt + 4 * q) = hv;
        *(uint2v*)(ptrS[mt] + dstep) = hv;
      }
    }
#pragma unroll
    for (int mt = 0; mt < 2; ++mt) {
      ptrS[mt] += 2 * dstep;
      curA[mt] = infA[mt];
      curB[mt] = infB[mt];
      infA[mt] = ldA[mt];
      infB[mt] = ldB[mt];
    }
    sync_lds();
  }
}

// ---------------------------------------------------------------------------
// convpool: out = tanh(max_t(h @ Wc_fb + ec) + bc). grid 512, 256 thr.
// ec gathered from (ecbase + row*ecstride); idx + ec software-pipelined.
// ---------------------------------------------------------------------------
__global__ __launch_bounds__(256, 2) void convpool_kernel(
    const int* __restrict__ idxC, const unsigned short* __restrict__ hsrc,
    const unsigned short* __restrict__ ecbase, int ecstride,
    const unsigned short* __restrict__ WcT, const float* __restrict__ bc,
    unsigned int* __restrict__ pooled) {
  const int btile = blockIdx.x & 15;
  const int tch = blockIdx.x >> 4;
  const int b0 = btile * 16;
  const int t0 = tch * 16;
  const int tid = threadIdx.x;
  const int w = tid >> 6, lane = tid & 63, q = lane >> 4, l15 = lane & 15;

  __shared__ __attribute__((aligned(16))) unsigned short tile[2][32][258];

  short8 wfr[2][16];
#pragma unroll
  for (int mt = 0; mt < 2; ++mt)
#pragma unroll
    for (int kt = 0; kt < 16; ++kt) {
      const int krow = kt < 8 ? kt * 32 : 384 + (kt - 8) * 32;
      wfr[mt][kt] = *(const short8*)(WcT +
                                     (size_t)(32 * w + 16 * mt + l15) * 640 +
                                     krow + q * 8);
    }
  float4v bv[2];
#pragma unroll
  for (int mt = 0; mt < 2; ++mt)
    bv[mt] = *(const float4v*)(bc + 32 * w + 16 * mt + 4 * q);

  float4v mx[2];
  mx[0] = (float4v){-1e30f, -1e30f, -1e30f, -1e30f};
  mx[1] = mx[0];

  const int su = tid >> 3, ssub = tid & 7;
  const int srow = su < 16 ? (b0 + su) : (256 + b0 + su - 16);
  const unsigned short* sbase = hsrc + (size_t)srow * T_ * 256 + ssub * 8;

  // idx/ec pipeline: icur -> ec for j, inxt -> idx for j+1
  const int* ip = idxC + (b0 + l15) * T_ + t0;
  const int ecofs = 32 * w + 4 * q;
  int inxt = ip[1];
  uint2v ecur[2];
  {
    const int i0 = ip[0];
#pragma unroll
    for (int mt = 0; mt < 2; ++mt)
      ecur[mt] = *(const uint2v*)(ecbase + (size_t)i0 * ecstride + ecofs +
                                  16 * mt);
  }

#pragma unroll
  for (int j2 = 0; j2 < 4; ++j2)
    *(short8*)&tile[0][su][ssub * 8 + j2 * 64] =
        *(const short8*)(sbase + (size_t)t0 * 256 + j2 * 64);
  sync_lds();

#pragma unroll 1
  for (int j = 0; j < 16; ++j) {
    const int t = t0 + j;
    const int buf = j & 1;
    if (j < 15) {
#pragma unroll
      for (int j2 = 0; j2 < 4; ++j2)
        *(short8*)&tile[buf ^ 1][su][ssub * 8 + j2 * 64] =
            *(const short8*)(sbase + (size_t)(t + 1) * 256 + j2 * 64);
    }
    // gather ec for j+1; load idx for j+2
    uint2v enx[2];
    if (j < 15) {
#pragma unroll
      for (int mt = 0; mt < 2; ++mt)
        enx[mt] = *(const uint2v*)(ecbase + (size_t)inxt * ecstride + ecofs +
                                   16 * mt);
    } else {
      enx[0] = ecur[0];
      enx[1] = ecur[1];
    }
    inxt = ip[j + 2 < 16 ? j + 2 : 15];

    float4v acc[2];
    acc[0] = (float4v){0.f, 0.f, 0.f, 0.f};
    acc[1] = (float4v){0.f, 0.f, 0.f, 0.f};
#pragma unroll
    for (int kt = 0; kt < 16; ++kt) {
      const int u = 2 * (kt & 7) + (q >> 1) + ((kt >= 8) ? 16 : 0);
      const unsigned short* tb = &tile[buf][u][128 * (q & 1) + 4 * l15];
      uint2v c1 = *(const uint2v*)tb;
      uint2v c2 = *(const uint2v*)(tb + 64);
      union { unsigned uu[4]; short8 s; } cv;
      cv.uu[0] = c1.x; cv.uu[1] = c1.y; cv.uu[2] = c2.x; cv.uu[3] = c2.y;
      acc[0] = __builtin_amdgcn_mfma_f32_16x16x32_bf16(wfr[0][kt], cv.s,
                                                       acc[0], 0, 0, 0);
      acc[1] = __builtin_amdgcn_mfma_f32_16x16x32_bf16(wfr[1][kt], cv.s,
                                                       acc[1], 0, 0, 0);
    }
#pragma unroll
    for (int mt = 0; mt < 2; ++mt) {
      float4v v = acc[mt] + (float4v){lo16f(ecur[mt].x), hi16f(ecur[mt].x),
                                      lo16f(ecur[mt].y), hi16f(ecur[mt].y)};
#pragma unroll
      for (int i = 0; i < 4; ++i) mx[mt][i] = fmaxf(mx[mt][i], v[i]);
    }
    ecur[0] = enx[0];
    ecur[1] = enx[1];
    sync_lds();
  }
#pragma unroll
  for (int mt = 0; mt < 2; ++mt)
#pragma unroll
    for (int i = 0; i < 4; ++i)
      atomicMax(pooled + (b0 + l15) * C_ + 32 * w + 16 * mt + 4 * q + i,
                enc_f(fast_tanh(mx[mt][i] + bv[mt][i])));
}

// ---------------------------------------------------------------------------
// dense: out = sigmoid(pooled @ Wd + bd)  [256,128]@[128,2]
// ---------------------------------------------------------------------------
__global__ __launch_bounds__(256) void dense_kernel(
    const unsigned int* __restrict__ pooled, const float* __restrict__ Wd,
    const float* __restrict__ bd, float* __restrict__ out) {
  int b = threadIdx.x;
  float s0 = bd[0], s1 = bd[1];
#pragma unroll 4
  for (int c = 0; c < C_; ++c) {
    float f = dec_f(pooled[b * C_ + c]);
    s0 += f * Wd[c * 2 + 0];
    s1 += f * Wd[c * 2 + 1];
  }
  out[b * 2 + 0] = 1.f / (1.f + __expf(-s0));
  out[b * 2 + 1] = 1.f / (1.f + __expf(-s1));
}

// ---------------------------------------------------------------------------
extern "C" void kernel_launch(void* const* d_in, const int* in_sizes, int n_in,
                              void* d_out, int out_size, void* d_ws, size_t ws_size,
                              hipStream_t stream) {
  const int* idxC = (const int*)d_in[0];
  const int* idxL = (const int*)d_in[1];
  const int* idxR = (const int*)d_in[2];
  const float* emb = (const float*)d_in[3];
  const float* Wf = (const float*)d_in[4];
  const float* Uf = (const float*)d_in[5];
  const float* bf_ = (const float*)d_in[6];
  const float* Wb = (const float*)d_in[7];
  const float* Ub = (const float*)d_in[8];
  const float* bb_ = (const float*)d_in[9];
  const float* Wc = (const float*)d_in[10];
  const float* bc = (const float*)d_in[11];
  const float* Wd = (const float*)d_in[12];
  const float* bd = (const float*)d_in[13];

  char* ws = (char*)d_ws;
  unsigned int* pooled = (unsigned int*)ws;                      //   131,072 B
  unsigned short* WfT = (unsigned short*)(ws + 131072);          //    65,536 B
  unsigned short* WbT = (unsigned short*)(ws + 196608);          //    65,536 B
  unsigned short* WcT = (unsigned short*)(ws + 262144);          //   163,840 B
  unsigned short* UfT = (unsigned short*)(ws + 425984);          //   131,072 B
  unsigned short* UbT = (unsigned short*)(ws + 557056);          //   131,072 B
  unsigned short* WT_all = (unsigned short*)(ws + 688128);       //   163,840 B
  float* biasEW = (float*)(ws + 851968);                         //     2,560 B
  unsigned short* big1 = (unsigned short*)(ws + 1048576);        // 134,217,728 B (hstore / xwh)
  unsigned short* big2 = (unsigned short*)(ws + 135266304);      // EW 64,000,000 or ECmid 12,800,000

  const bool newpath = ws_size >= 199266304ull;

  hipMemsetAsync(pooled, 0, B_ * C_ * sizeof(unsigned int), stream);
  prep_kernel<<<64, 256, 0, stream>>>(Wf, Wb, Wc, Uf, Ub, bf_, bb_, WfT, WbT,
                                      WcT, UfT, UbT, WT_all, biasEW);
  if (newpath) {
    ew_kernel<<<V_ / 16, 256, 0, stream>>>(emb, WT_all, biasEW, big2);
    rnn_gather_kernel<<<32, 512, 0, stream>>>(idxL, idxR, big2, UfT, UbT,
                                              big1);
    convpool_kernel<<<512, 256, 0, stream>>>(idxC, big1, big2 + 512, 640, WcT,
                                             bc, pooled);
  } else {
    embxw_kernel<<<dim3(128, 16, 2), 256, 0, stream>>>(idxL, idxR, emb, WfT,
                                                       WbT, bf_, bb_, big1);
    ewmid_kernel<<<V_ / 16, 256, 0, stream>>>(emb, WcT, big2);
    rnn_inplace_kernel<<<32, 512, 0, stream>>>(big1, UfT, UbT);
    convpool_kernel<<<512, 256, 0, stream>>>(idxC, big1, big2, 128, WcT, bc,
                                             pooled);
  }
  dense_kernel<<<1, 256, 0, stream>>>(pooled, Wd, bd, (float*)d_out);
}

// Round 12
// 606.164 us; speedup vs baseline: 1.4098x; 1.4098x over previous
//
#include <hip/hip_runtime.h>
#include <hip/hip_bf16.h>

// RCNN: bidirectional simple-RNN + conv1x1 + global max pool + dense sigmoid
// B=256 T=512 V=50000 E=128 H=256 C=128
//
// Round-12 = R7 (measured 629.8 us, best so far) + pipelined/widened embxw.
//  - x[B*T][640] bf16 rows: [0,256) xw_f->h_f units, [256,384) e_cur units
//    (q-half split), [384,640) xw_b->h_b units. rnn overwrites xw with h in
//    place (same block, race-free).
//  - rnn: R4 config (32 blocks = 16 btiles x 2 dirs, 8 waves x 32 cols,
//    2 same-chain waves/SIMD, C-seeded MFMA, T-unroll x2, prefetch-4,
//    LDS-only barrier) — measured 373 us. Structural floor for this
//    decomposition (dual-chain/1-wave/gather-seed/fused-conv all measured
//    worse: R3/R5/R6/R9/R11).
//  - embxw: NEW — 8-t blocks, all idx up front, emb gathers software-
//    pipelined one t ahead (R7 exposed a full gather latency per t).
//  - convpool: R7 verbatim (LDS-staged x rows, 20-kt GEMM, tanh after max).

#define B_ 256
#define T_ 512
#define E_ 128
#define H_ 256
#define C_ 128

typedef __attribute__((ext_vector_type(8))) short short8;
typedef __attribute__((ext_vector_type(4))) float float4v;
typedef __attribute__((ext_vector_type(2))) unsigned int uint2v;

__device__ inline unsigned short f2bf(float f) {
  unsigned u = __float_as_uint(f);
  u += 0x7fffu + ((u >> 16) & 1u);  // RNE
  return (unsigned short)(u >> 16);
}
__device__ inline unsigned pkbf(float a, float b) {
  __hip_bfloat162 h2 = __float22bfloat162_rn(float2{a, b});
  union { __hip_bfloat162 h; unsigned u; } cv;
  cv.h = h2;
  return cv.u;
}
__device__ inline float lo16f(unsigned u) { return __uint_as_float(u << 16); }
__device__ inline float hi16f(unsigned u) { return __uint_as_float(u & 0xffff0000u); }
__device__ inline float fast_tanh(float x) {
  float e = __expf(2.f * x);                 // inf ok -> 1
  float r = __builtin_amdgcn_rcpf(e + 1.f);
  return __builtin_fmaf(-2.f, r, 1.f);
}
__device__ inline unsigned enc_f(float f) {
  unsigned u = __float_as_uint(f);
  return (u & 0x80000000u) ? ~u : (u | 0x80000000u);
}
__device__ inline float dec_f(unsigned key) {
  unsigned bits = (key & 0x80000000u) ? (key ^ 0x80000000u) : ~key;
  return __uint_as_float(bits);
}
__device__ inline void sync_lds() {
  asm volatile("s_waitcnt lgkmcnt(0)\n\ts_barrier" ::: "memory");
}

// ---------------------------------------------------------------------------
// prep: WfT/WbT:[256][128] WcT:[128][640] UfT/UbT:[256][256] (all [n][k]).
// Coalesced reads, strided writes. Also zero-inits pooled (replaces memset).
// ---------------------------------------------------------------------------
__global__ __launch_bounds__(256) void prep_kernel(
    const float* __restrict__ Wf, const float* __restrict__ Wb,
    const float* __restrict__ Wc, const float* __restrict__ Uf,
    const float* __restrict__ Ub,
    unsigned short* __restrict__ WfT, unsigned short* __restrict__ WbT,
    unsigned short* __restrict__ WcT, unsigned short* __restrict__ UfT,
    unsigned short* __restrict__ UbT, unsigned int* __restrict__ pooled) {
  int gid = blockIdx.x * 256 + threadIdx.x;
  int stride = gridDim.x * 256;
  for (int i = gid; i < 128 * 256; i += stride) {  // Wf/Wb [128][256]
    int k = i >> 8, n = i & 255;
    WfT[n * 128 + k] = f2bf(Wf[i]);
    WbT[n * 128 + k] = f2bf(Wb[i]);
  }
  for (int i = gid; i < 640 * 128; i += stride) {  // Wc [640][128]
    int k = i >> 7, n = i & 127;
    WcT[n * 640 + k] = f2bf(Wc[i]);
  }
  for (int i = gid; i < 256 * 256; i += stride) {  // Uf/Ub [256][256]
    int k = i >> 8, n = i & 255;
    UfT[n * 256 + k] = f2bf(Uf[i]);
    UbT[n * 256 + k] = f2bf(Ub[i]);
  }
  for (int i = gid; i < B_ * C_; i += stride) pooled[i] = 0u;
}

// ---------------------------------------------------------------------------
// embxw: dirs 0/1: xw^T = W^T e^T + b, packed units into x; dir 2: e_cur
// gather into q-half-split units [256,384). grid (64 t-octs, 16 btiles, 3),
// 256 thr. emb gathers software-pipelined one t ahead.
// ---------------------------------------------------------------------------
__global__ __launch_bounds__(256) void embxw_kernel(
    const int* __restrict__ idxL, const int* __restrict__ idxR,
    const int* __restrict__ idxC, const float* __restrict__ emb,
    const unsigned short* __restrict__ WfT, const unsigned short* __restrict__ WbT,
    const float* __restrict__ bfv, const float* __restrict__ bbv,
    unsigned short* __restrict__ x) {
  const int dir = blockIdx.z;
  const int t0 = blockIdx.x * 8;
  const int b0 = blockIdx.y * 16;
  const int tid = threadIdx.x;
  const int w = tid >> 6, lane = tid & 63, q = lane >> 4, l15 = lane & 15;

  if (dir == 2) {  // e_cur gather: wave w covers t0+2w, t0+2w+1
#pragma unroll
    for (int jj = 0; jj < 2; ++jj) {
      const int t = t0 + 2 * w + jj;
      const int er = idxC[(b0 + l15) * T_ + t];
      const float* ep = emb + (size_t)er * E_;
#pragma unroll
      for (int u = 0; u < 8; ++u) {
        float4v a = *(const float4v*)(ep + 16 * u + 4 * q);
        uint2v pk = {pkbf(a[0], a[1]), pkbf(a[2], a[3])};
        int row = b0 + u + 8 * (q >> 1);
        *(uint2v*)(x + ((size_t)row * T_ + t) * 640 + 256 + 64 * (q & 1) +
                   4 * l15) = pk;
      }
    }
    return;
  }

  const int* __restrict__ idx = dir ? idxR : idxL;
  const unsigned short* __restrict__ WT = dir ? WbT : WfT;
  const float* __restrict__ bias = dir ? bbv : bfv;

  short8 wfr[4][4];
#pragma unroll
  for (int mt = 0; mt < 4; ++mt)
#pragma unroll
    for (int kt = 0; kt < 4; ++kt)
      wfr[mt][kt] = *(const short8*)(WT + (64 * w + 16 * mt + l15) * 128 +
                                     kt * 32 + q * 8);
  float4v bv[4];
#pragma unroll
  for (int mt = 0; mt < 4; ++mt)
    bv[mt] = *(const float4v*)(bias + 64 * w + 16 * mt + 4 * q);

  // all 8 idx up front
  int er[8];
#pragma unroll
  for (int j = 0; j < 8; ++j) er[j] = idx[(b0 + l15) * T_ + t0 + j];

  // prologue gather for j=0
  float4v g[8];
#pragma unroll
  for (int kt = 0; kt < 4; ++kt) {
    const float* p8 = emb + (size_t)er[0] * E_ + kt * 32 + q * 8;
    g[2 * kt] = *(const float4v*)p8;
    g[2 * kt + 1] = *(const float4v*)(p8 + 4);
  }

#pragma unroll 1
  for (int j = 0; j < 8; ++j) {
    float4v gn[8];
    if (j < 7) {  // prefetch next t's emb row while computing this one
#pragma unroll
      for (int kt = 0; kt < 4; ++kt) {
        const float* p8 = emb + (size_t)er[j + 1] * E_ + kt * 32 + q * 8;
        gn[2 * kt] = *(const float4v*)p8;
        gn[2 * kt + 1] = *(const float4v*)(p8 + 4);
      }
    }
    short8 efr[4];
#pragma unroll
    for (int kt = 0; kt < 4; ++kt) {
      union { unsigned u[4]; short8 s; } cv;
      cv.u[0] = pkbf(g[2 * kt][0], g[2 * kt][1]);
      cv.u[1] = pkbf(g[2 * kt][2], g[2 * kt][3]);
      cv.u[2] = pkbf(g[2 * kt + 1][0], g[2 * kt + 1][1]);
      cv.u[3] = pkbf(g[2 * kt + 1][2], g[2 * kt + 1][3]);
      efr[kt] = cv.s;
    }
    float4v acc[4];
#pragma unroll
    for (int mt = 0; mt < 4; ++mt) acc[mt] = (float4v){0.f, 0.f, 0.f, 0.f};
#pragma unroll
    for (int kt = 0; kt < 4; ++kt)
#pragma unroll
      for (int mt = 0; mt < 4; ++mt)
        acc[mt] = __builtin_amdgcn_mfma_f32_16x16x32_bf16(wfr[mt][kt], efr[kt],
                                                          acc[mt], 0, 0, 0);
    const int t = t0 + j;
#pragma unroll
    for (int mt = 0; mt < 4; ++mt) {
      float4v v = acc[mt] + bv[mt];
      uint2v pk = {pkbf(v[0], v[1]), pkbf(v[2], v[3])};
      *(uint2v*)(x + ((size_t)(b0 + 4 * w + mt) * T_ + t) * 640 + dir * 384 +
                 lane * 4) = pk;
    }
    if (j < 7) {
#pragma unroll
      for (int kk = 0; kk < 8; ++kk) g[kk] = gn[kk];
    }
  }
}

// ---------------------------------------------------------------------------
// rnn: h_t = tanh(U^T h ; C-seed = xw_t). One chain per block, 8 waves x
// 32 cols (2 same-chain waves/SIMD). 32 blocks. Unroll x2, prefetch 4.
// R4 configuration — measured 373 us (structural floor).
// ---------------------------------------------------------------------------
__global__ __launch_bounds__(512, 2) void rnn_kernel(
    unsigned short* x, const unsigned short* __restrict__ UfT,
    const unsigned short* __restrict__ UbT) {
  const int dir = blockIdx.x & 1;
  const int b0 = (blockIdx.x >> 1) * 16;
  const unsigned short* __restrict__ UT = dir ? UbT : UfT;
  const int xoff = dir ? 384 : 0;
  const int tstep = dir ? -1 : 1;
  const int t0 = dir ? (T_ - 1) : 0;
  const ptrdiff_t dstep = (ptrdiff_t)tstep * 640;  // shorts per t-step

  const int tid = threadIdx.x;
  const int wv = tid >> 6, lane = tid & 63, q = lane >> 4, l15 = lane & 15;

  // stride 280 shorts: b128 bank-start 4*(3*l15+q)%32 -> 2-way (free)
  __shared__ __attribute__((aligned(16))) unsigned short hbuf[2][16][280];
  unsigned short* hb0 = &hbuf[0][0][0];
  unsigned short* hb1 = &hbuf[1][0][0];

  for (int i = tid; i < 16 * 280; i += 512) hb0[i] = 0;

  short8 ufr[2][8];
#pragma unroll
  for (int mt = 0; mt < 2; ++mt)
#pragma unroll
    for (int kt = 0; kt < 8; ++kt)
      ufr[mt][kt] = *(const short8*)(UT + (32 * wv + 16 * mt + l15) * H_ +
                                     kt * 32 + q * 8);

  unsigned short* ptrS[2];        // store slot (step t of current pair)
  const unsigned short* ptrL[2];  // load slot (t + 4*tstep)
  uint2v curA[2], curB[2], infA[2], infB[2];
#pragma unroll
  for (int mt = 0; mt < 2; ++mt) {
    unsigned short* base =
        x + (size_t)(b0 + 2 * wv + mt) * T_ * 640 + xoff + lane * 4;
    unsigned short* bt = base + (ptrdiff_t)t0 * 640;
    curA[mt] = *(const uint2v*)(bt);
    curB[mt] = *(const uint2v*)(bt + dstep);
    infA[mt] = *(const uint2v*)(bt + 2 * dstep);
    infB[mt] = *(const uint2v*)(bt + 3 * dstep);
    ptrS[mt] = bt;
    ptrL[mt] = bt + 4 * dstep;
  }

  const unsigned lrd = l15 * 280;
  const unsigned lwr = l15 * 280 + 32 * wv;

  __syncthreads();

#pragma unroll 1
  for (int p = 0; p < 256; ++p) {
    uint2v ldA[2], ldB[2];
    if (p < 254) {
#pragma unroll
      for (int mt = 0; mt < 2; ++mt) {
        ldA[mt] = *(const uint2v*)(ptrL[mt]);
        ldB[mt] = *(const uint2v*)(ptrL[mt] + dstep);
      }
    } else {
#pragma unroll
      for (int mt = 0; mt < 2; ++mt) { ldA[mt] = infA[mt]; ldB[mt] = infB[mt]; }
    }
#pragma unroll
    for (int mt = 0; mt < 2; ++mt) ptrL[mt] += 2 * dstep;

    // ---- STEP A: read hb0, write hb1 ----
    {
      short8 afr[8];
#pragma unroll
      for (int kt = 0; kt < 8; ++kt)
        afr[kt] = *(const short8*)(hb0 + lrd + kt * 32 + q * 8);
      float4v acc[2];
#pragma unroll
      for (int mt = 0; mt < 2; ++mt)
        acc[mt] = (float4v){lo16f(curA[mt].x), hi16f(curA[mt].x),
                            lo16f(curA[mt].y), hi16f(curA[mt].y)};
#pragma unroll
      for (int kt = 0; kt < 8; ++kt)
#pragma unroll
        for (int mt = 0; mt < 2; ++mt)
          acc[mt] = __builtin_amdgcn_mfma_f32_16x16x32_bf16(
              ufr[mt][kt], afr[kt], acc[mt], 0, 0, 0);
#pragma unroll
      for (int mt = 0; mt < 2; ++mt) {
        uint2v hv = {pkbf(fast_tanh(acc[mt][0]), fast_tanh(acc[mt][1])),
                     pkbf(fast_tanh(acc[mt][2]), fast_tanh(acc[mt][3]))};
        *(uint2v*)(hb1 + lwr + 16 * mt + 4 * q) = hv;
        *(uint2v*)ptrS[mt] = hv;
      }
    }
    sync_lds();

    // ---- STEP B: read hb1, write hb0 ----
    {
      short8 afr[8];
#pragma unroll
      for (int kt = 0; kt < 8; ++kt)
        afr[kt] = *(const short8*)(hb1 + lrd + kt * 32 + q * 8);
      float4v acc[2];
#pragma unroll
      for (int mt = 0; mt < 2; ++mt)
        acc[mt] = (float4v){lo16f(curB[mt].x), hi16f(curB[mt].x),
                            lo16f(curB[mt].y), hi16f(curB[mt].y)};
#pragma unroll
      for (int kt = 0; kt < 8; ++kt)
#pragma unroll
        for (int mt = 0; mt < 2; ++mt)
          acc[mt] = __builtin_amdgcn_mfma_f32_16x16x32_bf16(
              ufr[mt][kt], afr[kt], acc[mt], 0, 0, 0);
#pragma unroll
      for (int mt = 0; mt < 2; ++mt) {
        uint2v hv = {pkbf(fast_tanh(acc[mt][0]), fast_tanh(acc[mt][1])),
                     pkbf(fast_tanh(acc[mt][2]), fast_tanh(acc[mt][3]))};
        *(uint2v*)(hb0 + lwr + 16 * mt + 4 * q) = hv;
        *(uint2v*)(ptrS[mt] + dstep) = hv;
      }
    }
#pragma unroll
    for (int mt = 0; mt < 2; ++mt) {
      ptrS[mt] += 2 * dstep;
      curA[mt] = infA[mt];
      curB[mt] = infB[mt];
      infA[mt] = ldA[mt];
      infB[mt] = ldB[mt];
    }
    sync_lds();
  }
}

// ---------------------------------------------------------------------------
// convpool: out = tanh(max_t(x_row @ Wc) + bc). R7 verbatim.
// grid (16 btiles x 32 tchunks), 256 thr (4 waves x 32 c-cols). LDS dbuf.
// ---------------------------------------------------------------------------
__global__ __launch_bounds__(256, 2) void convpool_kernel(
    const unsigned short* __restrict__ x, const unsigned short* __restrict__ WcT,
    const float* __restrict__ bc, unsigned int* __restrict__ pooled) {
  const int b0 = (blockIdx.x & 15) * 16;
  const int t0 = (blockIdx.x >> 4) * 16;
  const int tid = threadIdx.x;
  const int w = tid >> 6, lane = tid & 63, q = lane >> 4, l15 = lane & 15;

  __shared__ __attribute__((aligned(16))) unsigned short tile[2][16][648];

  short8 wfr[2][20];
#pragma unroll
  for (int ct = 0; ct < 2; ++ct)
#pragma unroll
    for (int kt = 0; kt < 20; ++kt)
      wfr[ct][kt] = *(const short8*)(WcT +
                                     (size_t)(32 * w + 16 * ct + l15) * 640 +
                                     kt * 32 + q * 8);
  float4v bv[2];
#pragma unroll
  for (int ct = 0; ct < 2; ++ct)
    bv[ct] = *(const float4v*)(bc + 32 * w + 16 * ct + 4 * q);

  float4v mx[2];
  mx[0] = (float4v){-1e30f, -1e30f, -1e30f, -1e30f};
  mx[1] = mx[0];

  const int srow = tid >> 4, ssub = tid & 15;
  {
    const unsigned short* src = x + ((size_t)(b0 + srow) * T_ + t0) * 640;
#pragma unroll
    for (int j = 0; j < 5; ++j)
      *(short8*)&tile[0][srow][ssub * 8 + j * 128] =
          *(const short8*)(src + ssub * 8 + j * 128);
  }
  __syncthreads();

#pragma unroll 1
  for (int j = 0; j < 16; ++j) {
    const int t = t0 + j;
    const int buf = j & 1;
    if (j < 15) {
      const unsigned short* src = x + ((size_t)(b0 + srow) * T_ + t + 1) * 640;
#pragma unroll
      for (int jj = 0; jj < 5; ++jj)
        *(short8*)&tile[buf ^ 1][srow][ssub * 8 + jj * 128] =
            *(const short8*)(src + ssub * 8 + jj * 128);
    }
    float4v acc[2];
    acc[0] = (float4v){0.f, 0.f, 0.f, 0.f};
    acc[1] = (float4v){0.f, 0.f, 0.f, 0.f};
#pragma unroll
    for (int kt = 0; kt < 20; ++kt) {
      int row, so1, so2;
      if (kt < 8) {
        row = 2 * kt + (q >> 1);
        so1 = 64 * (2 * (q & 1)) + 4 * l15;
        so2 = so1 + 64;
      } else if (kt < 12) {
        row = 2 * (kt - 8) + (q >> 1) + 8 * (q & 1);
        so1 = 256 + 4 * l15;
        so2 = 320 + 4 * l15;
      } else {
        row = 2 * (kt - 12) + (q >> 1);
        so1 = 384 + 64 * (2 * (q & 1)) + 4 * l15;
        so2 = so1 + 64;
      }
      union { unsigned u[4]; short8 s; } cv;
      uint2v c1 = *(const uint2v*)&tile[buf][row][so1];
      uint2v c2 = *(const uint2v*)&tile[buf][row][so2];
      cv.u[0] = c1.x; cv.u[1] = c1.y; cv.u[2] = c2.x; cv.u[3] = c2.y;
      acc[0] = __builtin_amdgcn_mfma_f32_16x16x32_bf16(wfr[0][kt], cv.s,
                                                       acc[0], 0, 0, 0);
      acc[1] = __builtin_amdgcn_mfma_f32_16x16x32_bf16(wfr[1][kt], cv.s,
                                                       acc[1], 0, 0, 0);
    }
#pragma unroll
    for (int ct = 0; ct < 2; ++ct)
#pragma unroll
      for (int i = 0; i < 4; ++i)
        mx[ct][i] = fmaxf(mx[ct][i], acc[ct][i]);  // pre-activation max
    __syncthreads();
  }
#pragma unroll
  for (int ct = 0; ct < 2; ++ct)
#pragma unroll
    for (int i = 0; i < 4; ++i)
      atomicMax(pooled + (b0 + l15) * C_ + 32 * w + 16 * ct + 4 * q + i,
                enc_f(fast_tanh(mx[ct][i] + bv[ct][i])));
}

// ---------------------------------------------------------------------------
// dense: out = sigmoid(pooled @ Wd + bd)  [256,128]@[128,2]
// ---------------------------------------------------------------------------
__global__ __launch_bounds__(256) void dense_kernel(
    const unsigned int* __restrict__ pooled, const float* __restrict__ Wd,
    const float* __restrict__ bd, float* __restrict__ out) {
  int b = threadIdx.x;
  float s0 = bd[0], s1 = bd[1];
#pragma unroll 4
  for (int c = 0; c < C_; ++c) {
    float f = dec_f(pooled[b * C_ + c]);
    s0 += f * Wd[c * 2 + 0];
    s1 += f * Wd[c * 2 + 1];
  }
  out[b * 2 + 0] = 1.f / (1.f + __expf(-s0));
  out[b * 2 + 1] = 1.f / (1.f + __expf(-s1));
}

// ---------------------------------------------------------------------------
extern "C" void kernel_launch(void* const* d_in, const int* in_sizes, int n_in,
                              void* d_out, int out_size, void* d_ws, size_t ws_size,
                              hipStream_t stream) {
  const int* idxC = (const int*)d_in[0];
  const int* idxL = (const int*)d_in[1];
  const int* idxR = (const int*)d_in[2];
  const float* emb = (const float*)d_in[3];
  const float* Wf = (const float*)d_in[4];
  const float* Uf = (const float*)d_in[5];
  const float* bf_ = (const float*)d_in[6];
  const float* Wb = (const float*)d_in[7];
  const float* Ub = (const float*)d_in[8];
  const float* bb_ = (const float*)d_in[9];
  const float* Wc = (const float*)d_in[10];
  const float* bc = (const float*)d_in[11];
  const float* Wd = (const float*)d_in[12];
  const float* bd = (const float*)d_in[13];

  char* ws = (char*)d_ws;
  unsigned short* x = (unsigned short*)ws;                          // 167,772,160 B
  unsigned int* pooled = (unsigned int*)(ws + 167772160);           //     131,072 B
  unsigned short* WfT = (unsigned short*)(ws + 167772160 + 131072); //      65,536 B
  unsigned short* WbT = WfT + 256 * 128;
  unsigned short* WcT = WbT + 256 * 128;
  unsigned short* UfT = WcT + 128 * 640;
  unsigned short* UbT = UfT + 256 * 256;

  prep_kernel<<<64, 256, 0, stream>>>(Wf, Wb, Wc, Uf, Ub, WfT, WbT, WcT, UfT,
                                      UbT, pooled);
  embxw_kernel<<<dim3(64, 16, 3), 256, 0, stream>>>(idxL, idxR, idxC, emb,
                                                    WfT, WbT, bf_, bb_, x);
  rnn_kernel<<<32, 512, 0, stream>>>(x, UfT, UbT);
  convpool_kernel<<<512, 256, 0, stream>>>(x, WcT, bc, pooled);
  dense_kernel<<<1, 256, 0, stream>>>(pooled, Wd, bd, (float*)d_out);
}